// Round 3
// baseline (159.745 us; speedup 1.0000x reference)
//
#include <hip/hip_runtime.h>

// out = F_amp(MLP(z_i, z_j, sep_xy2)) * (dxy / sep_r2)
// 2-deep software pipeline: each thread owns 2 pairs (4 elements).
// All 6 float4 loads issued up front; group-1 loads overlap group-0 compute.

typedef float f32x4 __attribute__((ext_vector_type(4)));

__device__ __forceinline__ float lrelu(float x) {
    return fmaxf(x, 0.1f * x);   // alpha=0.1 leaky relu
}

__device__ __forceinline__ float tanh_fast(float x) {
    // tanh(x) = 1 - 2/(exp(2x)+1); v_exp + v_rcp, exact limits at +-inf
    float e = __expf(2.0f * x);
    return 1.0f - 2.0f * __builtin_amdgcn_rcpf(e + 1.0f);
}

struct Weights {
    const float* __restrict__ W1; const float* __restrict__ b1;
    const float* __restrict__ W2; const float* __restrict__ b2;
    const float* __restrict__ W3; const float* __restrict__ b3;
    const float* __restrict__ W4; const float* __restrict__ b4;
};

// Compute one element: 6 input floats -> 2 output floats.
__device__ __forceinline__ void mlp_elem(const float xv[6], const Weights& w,
                                         float& o0, float& o1) {
    float dx = xv[3] - xv[0];
    float dy = xv[4] - xv[1];
    float dz = xv[5] - xv[2];
    float sep_xy2 = fmaf(dx, dx, dy * dy);
    float sep_r2  = fmaf(dz, dz, sep_xy2);
    float inv_r2  = __builtin_amdgcn_rcpf(sep_r2);

    float z0 = xv[2], z1 = xv[5], z2 = sep_xy2;

    float h1[10];
    #pragma unroll
    for (int j = 0; j < 10; ++j) {
        float a = w.b1[j];
        a = fmaf(z0, w.W1[0 * 10 + j], a);
        a = fmaf(z1, w.W1[1 * 10 + j], a);
        a = fmaf(z2, w.W1[2 * 10 + j], a);
        h1[j] = lrelu(a);
    }

    float h2[10];
    #pragma unroll
    for (int j = 0; j < 10; ++j) {
        float a = w.b2[j];
        #pragma unroll
        for (int i = 0; i < 10; ++i) a = fmaf(h1[i], w.W2[i * 10 + j], a);
        h2[j] = tanh_fast(a);
    }

    float h3[10];
    #pragma unroll
    for (int j = 0; j < 10; ++j) {
        float a = w.b3[j];
        #pragma unroll
        for (int i = 0; i < 10; ++i) a = fmaf(h2[i], w.W3[i * 10 + j], a);
        h3[j] = lrelu(a);
    }

    float f = w.b4[0];
    #pragma unroll
    for (int i = 0; i < 10; ++i) f = fmaf(h3[i], w.W4[i], f);

    float s = f * inv_r2;
    o0 = s * dx;
    o1 = s * dy;
}

__device__ __forceinline__ f32x4 mlp_pair(const f32x4& A, const f32x4& B,
                                          const f32x4& C, const Weights& w) {
    float x0[6] = {A[0], A[1], A[2], A[3], B[0], B[1]};
    float x1[6] = {B[2], B[3], C[0], C[1], C[2], C[3]};
    float o0, o1, o2, o3;
    mlp_elem(x0, w, o0, o1);
    mlp_elem(x1, w, o2, o3);
    f32x4 o;
    o[0] = o0; o[1] = o1; o[2] = o2; o[3] = o3;
    return o;
}

__global__ void __launch_bounds__(256) fused_mlp_kernel(
    const float* __restrict__ in,
    const float* __restrict__ W1, const float* __restrict__ b1,
    const float* __restrict__ W2, const float* __restrict__ b2,
    const float* __restrict__ W3, const float* __restrict__ b3,
    const float* __restrict__ W4, const float* __restrict__ b4,
    float* __restrict__ out, int npairs)
{
    const Weights w = {W1, b1, W2, b2, W3, b3, W4, b4};
    int tid = blockIdx.x * blockDim.x + threadIdx.x;
    int stride = gridDim.x * blockDim.x;
    int p0 = tid;
    int p1 = tid + stride;
    if (p0 >= npairs) return;

    const f32x4* in4 = reinterpret_cast<const f32x4*>(in);
    f32x4* out4 = reinterpret_cast<f32x4*>(out);

    // Issue ALL loads up front; group-1 loads stay in flight during
    // group-0 compute (~760 VALU instrs of cover).
    f32x4 A0 = __builtin_nontemporal_load(&in4[3 * p0 + 0]);
    f32x4 B0 = __builtin_nontemporal_load(&in4[3 * p0 + 1]);
    f32x4 C0 = __builtin_nontemporal_load(&in4[3 * p0 + 2]);

    bool has1 = (p1 < npairs);
    f32x4 A1 = {}, B1 = {}, C1 = {};
    if (has1) {
        A1 = __builtin_nontemporal_load(&in4[3 * p1 + 0]);
        B1 = __builtin_nontemporal_load(&in4[3 * p1 + 1]);
        C1 = __builtin_nontemporal_load(&in4[3 * p1 + 2]);
    }

    f32x4 o0 = mlp_pair(A0, B0, C0, w);
    __builtin_nontemporal_store(o0, &out4[p0]);

    if (has1) {
        f32x4 o1 = mlp_pair(A1, B1, C1, w);
        __builtin_nontemporal_store(o1, &out4[p1]);
    }
}

extern "C" void kernel_launch(void* const* d_in, const int* in_sizes, int n_in,
                              void* d_out, int out_size, void* d_ws, size_t ws_size,
                              hipStream_t stream) {
    const float* in = (const float*)d_in[0];
    const float* W1 = (const float*)d_in[1];
    const float* b1 = (const float*)d_in[2];
    const float* W2 = (const float*)d_in[3];
    const float* b2 = (const float*)d_in[4];
    const float* W3 = (const float*)d_in[5];
    const float* b3 = (const float*)d_in[6];
    const float* W4 = (const float*)d_in[7];
    const float* b4 = (const float*)d_in[8];
    float* out = (float*)d_out;

    int npairs = out_size / 4;                    // 4 output floats per pair
    int nthreads = (npairs + 1) / 2;              // 2 pairs per thread
    int blocks = (nthreads + 255) / 256;
    fused_mlp_kernel<<<blocks, 256, 0, stream>>>(
        in, W1, b1, W2, b2, W3, b3, W4, b4, out, npairs);
}

// Round 4
// 68.800 us; speedup vs baseline: 2.3219x; 2.3219x over previous
//
#include <hip/hip_runtime.h>

// out = F_amp(MLP(z_i, z_j, sep_xy2)) * (dxy / sep_r2)
// R0 structure (1 pair = 2 elements per thread, 3x float4 load, 1x float4
// store) but the two elements are PACKED into f32x2 lanes so the MLP's
// ~440 scalar FMAs become ~220 v_pk_fma_f32 (dual-issue packed fp32).

typedef float f32x4 __attribute__((ext_vector_type(4)));
typedef float f32x2 __attribute__((ext_vector_type(2)));

__device__ __forceinline__ f32x2 sp(float w) { return (f32x2){w, w}; }

__device__ __forceinline__ f32x2 fma2(f32x2 a, f32x2 b, f32x2 c) {
    return __builtin_elementwise_fma(a, b, c);
}

__device__ __forceinline__ f32x2 lrelu2(f32x2 x) {
    // leaky relu alpha=0.1 == max(x, 0.1x)
    return __builtin_elementwise_max(x, x * 0.1f);
}

__device__ __forceinline__ float tanh_fast(float x) {
    // tanh(x) = 1 - 2/(exp(2x)+1); v_exp + v_rcp, exact limits at +-inf
    float e = __expf(2.0f * x);
    return 1.0f - 2.0f * __builtin_amdgcn_rcpf(e + 1.0f);
}

__device__ __forceinline__ f32x2 tanh2(f32x2 a) {
    return (f32x2){tanh_fast(a[0]), tanh_fast(a[1])};
}

__global__ void __launch_bounds__(256) fused_mlp_kernel(
    const float* __restrict__ in,
    const float* __restrict__ W1, const float* __restrict__ b1,
    const float* __restrict__ W2, const float* __restrict__ b2,
    const float* __restrict__ W3, const float* __restrict__ b3,
    const float* __restrict__ W4, const float* __restrict__ b4,
    float* __restrict__ out, int npairs)
{
    int p = blockIdx.x * blockDim.x + threadIdx.x;
    if (p >= npairs) return;

    const f32x4* in4 = reinterpret_cast<const f32x4*>(in);
    f32x4 A = in4[3 * p + 0];
    f32x4 B = in4[3 * p + 1];
    f32x4 C = in4[3 * p + 2];

    // element0 = {A.x A.y A.z A.w B.x B.y}, element1 = {B.z B.w C.x C.y C.z C.w}
    // pack: lane .x = element0, lane .y = element1
    f32x2 px0 = {A[0], B[2]}, py0 = {A[1], B[3]}, pz0 = {A[2], C[0]};
    f32x2 px1 = {A[3], C[1]}, py1 = {B[0], C[2]}, pz1 = {B[1], C[3]};

    f32x2 dx = px1 - px0;
    f32x2 dy = py1 - py0;
    f32x2 dz = pz1 - pz0;
    f32x2 sep_xy2 = fma2(dx, dx, dy * dy);
    f32x2 sep_r2  = fma2(dz, dz, sep_xy2);
    f32x2 inv_r2  = {__builtin_amdgcn_rcpf(sep_r2[0]),
                     __builtin_amdgcn_rcpf(sep_r2[1])};

    f32x2 Z0 = pz0;        // z_i
    f32x2 Z1 = pz1;        // z_j
    f32x2 Z2 = sep_xy2;    // sep_xy^2

    // Layer 1: [3] -> [10], leaky relu
    f32x2 h1[10];
    #pragma unroll
    for (int j = 0; j < 10; ++j) {
        f32x2 a = sp(b1[j]);
        a = fma2(Z0, sp(W1[0 * 10 + j]), a);
        a = fma2(Z1, sp(W1[1 * 10 + j]), a);
        a = fma2(Z2, sp(W1[2 * 10 + j]), a);
        h1[j] = lrelu2(a);
    }

    // Layer 2: [10] -> [10], tanh
    f32x2 h2[10];
    #pragma unroll
    for (int j = 0; j < 10; ++j) {
        f32x2 a = sp(b2[j]);
        #pragma unroll
        for (int i = 0; i < 10; ++i) a = fma2(h1[i], sp(W2[i * 10 + j]), a);
        h2[j] = tanh2(a);
    }

    // Layer 3: [10] -> [10], leaky relu
    f32x2 h3[10];
    #pragma unroll
    for (int j = 0; j < 10; ++j) {
        f32x2 a = sp(b3[j]);
        #pragma unroll
        for (int i = 0; i < 10; ++i) a = fma2(h2[i], sp(W3[i * 10 + j]), a);
        h3[j] = lrelu2(a);
    }

    // Layer 4: [10] -> [1]
    f32x2 f = sp(b4[0]);
    #pragma unroll
    for (int i = 0; i < 10; ++i) f = fma2(h3[i], sp(W4[i]), f);

    f32x2 s = f * inv_r2;
    f32x2 ox = s * dx;
    f32x2 oy = s * dy;

    f32x4 o;
    o[0] = ox[0]; o[1] = oy[0]; o[2] = ox[1]; o[3] = oy[1];
    reinterpret_cast<f32x4*>(out)[p] = o;
}

extern "C" void kernel_launch(void* const* d_in, const int* in_sizes, int n_in,
                              void* d_out, int out_size, void* d_ws, size_t ws_size,
                              hipStream_t stream) {
    const float* in = (const float*)d_in[0];
    const float* W1 = (const float*)d_in[1];
    const float* b1 = (const float*)d_in[2];
    const float* W2 = (const float*)d_in[3];
    const float* b2 = (const float*)d_in[4];
    const float* W3 = (const float*)d_in[5];
    const float* b3 = (const float*)d_in[6];
    const float* W4 = (const float*)d_in[7];
    const float* b4 = (const float*)d_in[8];
    float* out = (float*)d_out;

    int npairs = out_size / 4;          // 2 elements (4 output floats) per thread
    int blocks = (npairs + 255) / 256;
    fused_mlp_kernel<<<blocks, 256, 0, stream>>>(
        in, W1, b1, W2, b2, W3, b3, W4, b4, out, npairs);
}